// Round 1
// baseline (1431.160 us; speedup 1.0000x reference)
//
#include <hip/hip_runtime.h>

#define DDIM 64
#define EPS 0.1f
#define NORM_EPS 1e-12f

// ego_cur = concat(user, item); ego_next = 0
__global__ void init_kernel(const float* __restrict__ user, const float* __restrict__ item,
                            float* __restrict__ egoA, float* __restrict__ egoB,
                            int UD, int ND) {
    int i = blockIdx.x * blockDim.x + threadIdx.x;
    if (i < ND) {
        egoA[i] = (i < UD) ? user[i] : item[i - UD];
        egoB[i] = 0.0f;
    }
}

// one wave (64 lanes) per nonzero: y[row][d] += val * x[col][d]
__global__ void spmm_kernel(const int* __restrict__ row, const int* __restrict__ col,
                            const float* __restrict__ val, const float* __restrict__ x,
                            float* __restrict__ y, int nnz) {
    int gtid = blockIdx.x * blockDim.x + threadIdx.x;
    int wid = gtid >> 6;
    int lane = threadIdx.x & 63;
    int nwaves = (gridDim.x * blockDim.x) >> 6;
    for (int e = wid; e < nnz; e += nwaves) {
        int r = row[e];
        int c = col[e];
        float v = val[e];
        float xv = x[(size_t)c * DDIM + lane];
        unsafeAtomicAdd(&y[(size_t)r * DDIM + lane], v * xv);
    }
}

// one wave per node row:
//  rn = noise_row / max(||noise_row||, 1e-12)
//  ego += sign(ego) * rn * EPS          (in place)
//  out  = (first ? 0 : out) + ego * invL
//  zero_buf[row] = 0                    (prep next spmm target), optional
__global__ void perturb_kernel(float* __restrict__ ego, const float* __restrict__ noise,
                               float* __restrict__ zero_buf, float* __restrict__ out,
                               int N, int first, float invL) {
    int gtid = blockIdx.x * blockDim.x + threadIdx.x;
    int wid = gtid >> 6;
    int lane = threadIdx.x & 63;
    int nwaves = (gridDim.x * blockDim.x) >> 6;
    for (int n = wid; n < N; n += nwaves) {
        size_t idx = (size_t)n * DDIM + lane;
        float nv = noise[idx];
        float sq = nv * nv;
        #pragma unroll
        for (int off = 32; off > 0; off >>= 1) sq += __shfl_xor(sq, off, 64);
        float norm = sqrtf(sq);
        float rn = nv / fmaxf(norm, NORM_EPS);
        float e = ego[idx];
        float s = (e > 0.0f) ? 1.0f : ((e < 0.0f) ? -1.0f : 0.0f);
        float ep = e + s * rn * EPS;
        ego[idx] = ep;
        if (zero_buf) zero_buf[idx] = 0.0f;
        float o = ep * invL;
        out[idx] = first ? o : (out[idx] + o);
    }
}

extern "C" void kernel_launch(void* const* d_in, const int* in_sizes, int n_in,
                              void* d_out, int out_size, void* d_ws, size_t ws_size,
                              hipStream_t stream) {
    const float* user  = (const float*)d_in[0];
    const float* item  = (const float*)d_in[1];
    const int*   row   = (const int*)d_in[2];
    const int*   col   = (const int*)d_in[3];
    const float* val   = (const float*)d_in[4];
    const float* noise = (const float*)d_in[5];
    float* out = (float*)d_out;

    int UD = in_sizes[0];
    int ID = in_sizes[1];
    int ND = UD + ID;
    int N  = ND / DDIM;
    int nnz = in_sizes[2];
    int L  = in_sizes[5] / ND;

    float* egoA = (float*)d_ws;
    float* egoB = egoA + (size_t)ND;

    init_kernel<<<(ND + 255) / 256, 256, 0, stream>>>(user, item, egoA, egoB, UD, ND);

    float* cur = egoA;
    float* nxt = egoB;
    for (int k = 0; k < L; ++k) {
        spmm_kernel<<<2048, 256, 0, stream>>>(row, col, val, cur, nxt, nnz);
        perturb_kernel<<<1024, 256, 0, stream>>>(
            nxt, noise + (size_t)k * ND,
            (k + 1 < L) ? cur : nullptr, out, N, (k == 0) ? 1 : 0, 1.0f / (float)L);
        float* t = cur; cur = nxt; nxt = t;
    }
}

// Round 2
// 715.839 us; speedup vs baseline: 1.9993x; 1.9993x over previous
//
#include <hip/hip_runtime.h>

#define DDIM 64
#define EPS 0.1f
#define NORM_EPS 1e-12f

// ---------------- init: ego = concat(user, item) ----------------
__global__ void init_kernel(const float* __restrict__ user, const float* __restrict__ item,
                            float* __restrict__ egoA, int UD, int ND) {
    int i = blockIdx.x * blockDim.x + threadIdx.x;
    if (i < ND) egoA[i] = (i < UD) ? user[i] : item[i - UD];
}

__global__ void init_zero_kernel(const float* __restrict__ user, const float* __restrict__ item,
                                 float* __restrict__ egoA, float* __restrict__ egoB,
                                 int UD, int ND) {
    int i = blockIdx.x * blockDim.x + threadIdx.x;
    if (i < ND) {
        egoA[i] = (i < UD) ? user[i] : item[i - UD];
        egoB[i] = 0.0f;
    }
}

// ---------------- CSR build ----------------
__global__ void zero_int_kernel(int* __restrict__ p, int n) {
    int i = blockIdx.x * blockDim.x + threadIdx.x;
    if (i < n) p[i] = 0;
}

__global__ void hist_kernel(const int* __restrict__ row, int* __restrict__ cnt, int nnz) {
    int e = blockIdx.x * blockDim.x + threadIdx.x;
    if (e < nnz) atomicAdd(&cnt[row[e]], 1);
}

// block-wise inclusive scan (1024/block) + block sums
__global__ void scan1_kernel(const int* __restrict__ cnt, int* __restrict__ partial,
                             int* __restrict__ bsums, int n) {
    __shared__ int s[1024];
    int i = blockIdx.x * 1024 + threadIdx.x;
    int v = (i < n) ? cnt[i] : 0;
    s[threadIdx.x] = v;
    __syncthreads();
    for (int off = 1; off < 1024; off <<= 1) {
        int t = (threadIdx.x >= off) ? s[threadIdx.x - off] : 0;
        __syncthreads();
        s[threadIdx.x] += t;
        __syncthreads();
    }
    if (i < n) partial[i] = s[threadIdx.x];
    if (threadIdx.x == 1023) bsums[blockIdx.x] = s[1023];
}

// exclusive scan of block sums (small: ~147 entries)
__global__ void scan2_kernel(int* __restrict__ bsums, int nb) {
    if (blockIdx.x == 0 && threadIdx.x == 0) {
        int run = 0;
        for (int b = 0; b < nb; ++b) { int t = bsums[b]; bsums[b] = run; run += t; }
    }
}

// rowptr[i+1] = partial[i] + bsums[block]; rowptr[0] = 0
__global__ void scan3_kernel(const int* __restrict__ partial, const int* __restrict__ bsums,
                             int* __restrict__ rowptr, int n) {
    int i = blockIdx.x * 1024 + threadIdx.x;
    if (i < n) rowptr[i + 1] = partial[i] + bsums[blockIdx.x];
    if (i == 0) rowptr[0] = 0;
}

__global__ void scatter_kernel(const int* __restrict__ row, const int* __restrict__ col,
                               const float* __restrict__ val, const int* __restrict__ rowptr,
                               int* __restrict__ cursor, int2* __restrict__ edges, int nnz) {
    int e = blockIdx.x * blockDim.x + threadIdx.x;
    if (e < nnz) {
        int r = row[e];
        int pos = rowptr[r] + atomicAdd(&cursor[r], 1);
        edges[pos] = make_int2(col[e], __float_as_int(val[e]));
    }
}

// ---------------- fused layer: CSR spmm + perturb + out accumulate ----------------
// one wave per output row; lane = dim
__global__ void fused_layer_kernel(const int* __restrict__ rowptr, const int2* __restrict__ edges,
                                   const float* __restrict__ x, const float* __restrict__ noise,
                                   float* __restrict__ y, float* __restrict__ out,
                                   int N, int first, float invL) {
    int lane = threadIdx.x & 63;
    int r = (blockIdx.x * blockDim.x + threadIdx.x) >> 6;
    if (r >= N) return;

    int beg = __builtin_amdgcn_readfirstlane(rowptr[r]);
    int end = __builtin_amdgcn_readfirstlane(rowptr[r + 1]);

    float acc = 0.0f;
    for (int e = beg; e < end; ++e) {
        int2 ed = edges[e];  // wave-uniform 8B record -> scalar/broadcast load
        acc = fmaf(__int_as_float(ed.y), x[(size_t)ed.x * DDIM + lane], acc);
    }

    size_t idx = (size_t)r * DDIM + lane;
    float nv = noise[idx];
    float sq = nv * nv;
    #pragma unroll
    for (int off = 32; off > 0; off >>= 1) sq += __shfl_xor(sq, off, 64);
    float rn = nv / fmaxf(sqrtf(sq), NORM_EPS);

    float s = (acc > 0.0f) ? 1.0f : ((acc < 0.0f) ? -1.0f : 0.0f);
    float ep = acc + s * rn * EPS;
    y[idx] = ep;
    float o = ep * invL;
    out[idx] = first ? o : (out[idx] + o);
}

// ---------------- fallback path (round-1 kernels) ----------------
__global__ void spmm_kernel(const int* __restrict__ row, const int* __restrict__ col,
                            const float* __restrict__ val, const float* __restrict__ x,
                            float* __restrict__ y, int nnz) {
    int gtid = blockIdx.x * blockDim.x + threadIdx.x;
    int wid = gtid >> 6;
    int lane = threadIdx.x & 63;
    int nwaves = (gridDim.x * blockDim.x) >> 6;
    for (int e = wid; e < nnz; e += nwaves) {
        int r = row[e];
        int c = col[e];
        float v = val[e];
        unsafeAtomicAdd(&y[(size_t)r * DDIM + lane], v * x[(size_t)c * DDIM + lane]);
    }
}

__global__ void perturb_kernel(float* __restrict__ ego, const float* __restrict__ noise,
                               float* __restrict__ zero_buf, float* __restrict__ out,
                               int N, int first, float invL) {
    int gtid = blockIdx.x * blockDim.x + threadIdx.x;
    int wid = gtid >> 6;
    int lane = threadIdx.x & 63;
    int nwaves = (gridDim.x * blockDim.x) >> 6;
    for (int n = wid; n < N; n += nwaves) {
        size_t idx = (size_t)n * DDIM + lane;
        float nv = noise[idx];
        float sq = nv * nv;
        #pragma unroll
        for (int off = 32; off > 0; off >>= 1) sq += __shfl_xor(sq, off, 64);
        float rn = nv / fmaxf(sqrtf(sq), NORM_EPS);
        float e = ego[idx];
        float s = (e > 0.0f) ? 1.0f : ((e < 0.0f) ? -1.0f : 0.0f);
        float ep = e + s * rn * EPS;
        ego[idx] = ep;
        if (zero_buf) zero_buf[idx] = 0.0f;
        float o = ep * invL;
        out[idx] = first ? o : (out[idx] + o);
    }
}

extern "C" void kernel_launch(void* const* d_in, const int* in_sizes, int n_in,
                              void* d_out, int out_size, void* d_ws, size_t ws_size,
                              hipStream_t stream) {
    const float* user  = (const float*)d_in[0];
    const float* item  = (const float*)d_in[1];
    const int*   row   = (const int*)d_in[2];
    const int*   col   = (const int*)d_in[3];
    const float* val   = (const float*)d_in[4];
    const float* noise = (const float*)d_in[5];
    float* out = (float*)d_out;

    int UD = in_sizes[0];
    int ID = in_sizes[1];
    int ND = UD + ID;
    int N  = ND / DDIM;
    int nnz = in_sizes[2];
    int L  = in_sizes[5] / ND;
    float invL = 1.0f / (float)L;

    // ws layout (4B units): egoA(ND) | egoB(ND) | rowptr(N+2) | cnt(N) | partial(N) | bsums(1024) | edges(2*nnz)
    size_t ND_ = (size_t)ND;
    size_t ofs_rowptr  = 2 * ND_;
    size_t ofs_cnt     = ofs_rowptr + (size_t)(N + 2);
    size_t ofs_partial = ofs_cnt + (size_t)N;
    size_t ofs_bsums   = ofs_partial + (size_t)N;
    size_t ofs_edges   = ofs_bsums + 1024;   // all even -> 8B aligned
    size_t needed = (ofs_edges + 2ull * (size_t)nnz) * 4ull;

    float* egoA = (float*)d_ws;
    float* egoB = egoA + ND_;

    if (ws_size >= needed && (N % 2) == 0) {
        int* rowptr  = (int*)d_ws + ofs_rowptr;
        int* cnt     = (int*)d_ws + ofs_cnt;
        int* partial = (int*)d_ws + ofs_partial;
        int* bsums   = (int*)d_ws + ofs_bsums;
        int2* edges  = (int2*)((int*)d_ws + ofs_edges);

        int nb = (N + 1023) / 1024;

        init_kernel<<<(ND + 255) / 256, 256, 0, stream>>>(user, item, egoA, UD, ND);
        zero_int_kernel<<<(N + 255) / 256, 256, 0, stream>>>(cnt, N);
        hist_kernel<<<(nnz + 255) / 256, 256, 0, stream>>>(row, cnt, nnz);
        scan1_kernel<<<nb, 1024, 0, stream>>>(cnt, partial, bsums, N);
        scan2_kernel<<<1, 64, 0, stream>>>(bsums, nb);
        scan3_kernel<<<nb, 1024, 0, stream>>>(partial, bsums, rowptr, N);
        zero_int_kernel<<<(N + 255) / 256, 256, 0, stream>>>(cnt, N);
        scatter_kernel<<<(nnz + 255) / 256, 256, 0, stream>>>(row, col, val, rowptr, cnt, edges, nnz);

        float* cur = egoA;
        float* nxt = egoB;
        int blocks = (N * 64 + 255) / 256;
        for (int k = 0; k < L; ++k) {
            fused_layer_kernel<<<blocks, 256, 0, stream>>>(
                rowptr, edges, cur, noise + (size_t)k * ND_, nxt, out,
                N, (k == 0) ? 1 : 0, invL);
            float* t = cur; cur = nxt; nxt = t;
        }
    } else {
        // fallback: round-1 atomic path
        init_zero_kernel<<<(ND + 255) / 256, 256, 0, stream>>>(user, item, egoA, egoB, UD, ND);
        float* cur = egoA;
        float* nxt = egoB;
        for (int k = 0; k < L; ++k) {
            spmm_kernel<<<2048, 256, 0, stream>>>(row, col, val, cur, nxt, nnz);
            perturb_kernel<<<1024, 256, 0, stream>>>(
                nxt, noise + (size_t)k * ND_,
                (k + 1 < L) ? cur : nullptr, out, N, (k == 0) ? 1 : 0, invL);
            float* t = cur; cur = nxt; nxt = t;
        }
    }
}

// Round 3
// 492.278 us; speedup vs baseline: 2.9072x; 1.4541x over previous
//
#include <hip/hip_runtime.h>

#define DDIM 64
#define EPS 0.1f
#define NORM_EPS 1e-12f

// ---------------- init: ego = concat(user, item) ----------------
__global__ void init_kernel(const float* __restrict__ user, const float* __restrict__ item,
                            float* __restrict__ egoA, int UD, int ND) {
    int i = blockIdx.x * blockDim.x + threadIdx.x;
    if (i < ND) egoA[i] = (i < UD) ? user[i] : item[i - UD];
}

__global__ void init_zero_kernel(const float* __restrict__ user, const float* __restrict__ item,
                                 float* __restrict__ egoA, float* __restrict__ egoB,
                                 int UD, int ND) {
    int i = blockIdx.x * blockDim.x + threadIdx.x;
    if (i < ND) {
        egoA[i] = (i < UD) ? user[i] : item[i - UD];
        egoB[i] = 0.0f;
    }
}

// ---------------- CSR build ----------------
__global__ void zero_int_kernel(int* __restrict__ p, int n) {
    int i = blockIdx.x * blockDim.x + threadIdx.x;
    if (i < n) p[i] = 0;
}

// histogram + per-edge position within its row
__global__ void hist_kernel(const int* __restrict__ row, int* __restrict__ cnt,
                            int* __restrict__ pos, int nnz) {
    int e = blockIdx.x * blockDim.x + threadIdx.x;
    if (e < nnz) pos[e] = atomicAdd(&cnt[row[e]], 1);
}

// block-wise inclusive scan (1024/block) + block sums
__global__ void scan1_kernel(const int* __restrict__ cnt, int* __restrict__ partial,
                             int* __restrict__ bsums, int n) {
    __shared__ int s[1024];
    int i = blockIdx.x * 1024 + threadIdx.x;
    int v = (i < n) ? cnt[i] : 0;
    s[threadIdx.x] = v;
    __syncthreads();
    for (int off = 1; off < 1024; off <<= 1) {
        int t = (threadIdx.x >= off) ? s[threadIdx.x - off] : 0;
        __syncthreads();
        s[threadIdx.x] += t;
        __syncthreads();
    }
    if (i < n) partial[i] = s[threadIdx.x];
    if (threadIdx.x == 1023) bsums[blockIdx.x] = s[1023];
}

__global__ void scan2_kernel(int* __restrict__ bsums, int nb) {
    if (blockIdx.x == 0 && threadIdx.x == 0) {
        int run = 0;
        for (int b = 0; b < nb; ++b) { int t = bsums[b]; bsums[b] = run; run += t; }
    }
}

__global__ void scan3_kernel(const int* __restrict__ partial, const int* __restrict__ bsums,
                             int* __restrict__ rowptr, int n) {
    int i = blockIdx.x * 1024 + threadIdx.x;
    if (i < n) rowptr[i + 1] = partial[i] + bsums[blockIdx.x];
    if (i == 0) rowptr[0] = 0;
}

__global__ void scatter_kernel(const int* __restrict__ row, const int* __restrict__ col,
                               const float* __restrict__ val, const int* __restrict__ rowptr,
                               const int* __restrict__ pos, int2* __restrict__ edges, int nnz) {
    int e = blockIdx.x * blockDim.x + threadIdx.x;
    if (e < nnz) {
        int r = row[e];
        edges[rowptr[r] + pos[e]] = make_int2(col[e], __float_as_int(val[e]));
    }
}

// ---------------- fused layer: CSR spmm + perturb + out accumulate ----------------
// one wave per output row; 4 x 16-lane groups, group g handles edge e+g,
// each lane owns a float4 (dims sub*4 .. sub*4+3)
__global__ void fused_layer_kernel(const int* __restrict__ rowptr, const int2* __restrict__ edges,
                                   const float* __restrict__ x, const float* __restrict__ noise,
                                   float* __restrict__ y, float* __restrict__ out,
                                   int N, int first, float invL) {
    int lane = threadIdx.x & 63;
    int r = (blockIdx.x * blockDim.x + threadIdx.x) >> 6;
    if (r >= N) return;
    int g   = lane >> 4;   // edge group 0..3
    int sub = lane & 15;   // float4 index within row

    int beg = __builtin_amdgcn_readfirstlane(rowptr[r]);
    int end = __builtin_amdgcn_readfirstlane(rowptr[r + 1]);

    const float4* x4 = (const float4*)x;

    float4 acc0 = make_float4(0.f, 0.f, 0.f, 0.f);
    float4 acc1 = make_float4(0.f, 0.f, 0.f, 0.f);

    for (int e = beg; e < end; e += 8) {
        // quad 0: edges e+0..e+3 (e < end guaranteed)
        {
            int ee = e + g;
            bool act = ee < end;
            int2 ed = edges[act ? ee : beg];
            float v = act ? __int_as_float(ed.y) : 0.0f;
            float4 xv = x4[(size_t)ed.x * 16 + sub];
            acc0.x = fmaf(v, xv.x, acc0.x);
            acc0.y = fmaf(v, xv.y, acc0.y);
            acc0.z = fmaf(v, xv.z, acc0.z);
            acc0.w = fmaf(v, xv.w, acc0.w);
        }
        // quad 1: edges e+4..e+7 (wave-uniform branch)
        if (e + 4 < end) {
            int ee = e + 4 + g;
            bool act = ee < end;
            int2 ed = edges[act ? ee : beg];
            float v = act ? __int_as_float(ed.y) : 0.0f;
            float4 xv = x4[(size_t)ed.x * 16 + sub];
            acc1.x = fmaf(v, xv.x, acc1.x);
            acc1.y = fmaf(v, xv.y, acc1.y);
            acc1.z = fmaf(v, xv.z, acc1.z);
            acc1.w = fmaf(v, xv.w, acc1.w);
        }
    }

    float4 acc;
    acc.x = acc0.x + acc1.x;
    acc.y = acc0.y + acc1.y;
    acc.z = acc0.z + acc1.z;
    acc.w = acc0.w + acc1.w;

    // cross-group reduce: lanes {sub, sub+16, sub+32, sub+48} sum up
    #pragma unroll
    for (int off = 16; off <= 32; off <<= 1) {
        acc.x += __shfl_xor(acc.x, off, 64);
        acc.y += __shfl_xor(acc.y, off, 64);
        acc.z += __shfl_xor(acc.z, off, 64);
        acc.w += __shfl_xor(acc.w, off, 64);
    }

    // epilogue in group 0 only (16 lanes x float4 = full 64-dim row)
    if (g == 0) {
        const float4* n4 = (const float4*)noise;
        float4* y4 = (float4*)y;
        float4* o4 = (float4*)out;
        size_t ridx = (size_t)r * 16 + sub;

        float4 nv = n4[ridx];
        float sq = nv.x * nv.x + nv.y * nv.y + nv.z * nv.z + nv.w * nv.w;
        #pragma unroll
        for (int off = 1; off <= 8; off <<= 1) sq += __shfl_xor(sq, off, 64);
        float scale = EPS / fmaxf(sqrtf(sq), NORM_EPS);

        float4 ep;
        float s;
        s = (acc.x > 0.f) ? 1.f : ((acc.x < 0.f) ? -1.f : 0.f); ep.x = acc.x + s * nv.x * scale;
        s = (acc.y > 0.f) ? 1.f : ((acc.y < 0.f) ? -1.f : 0.f); ep.y = acc.y + s * nv.y * scale;
        s = (acc.z > 0.f) ? 1.f : ((acc.z < 0.f) ? -1.f : 0.f); ep.z = acc.z + s * nv.z * scale;
        s = (acc.w > 0.f) ? 1.f : ((acc.w < 0.f) ? -1.f : 0.f); ep.w = acc.w + s * nv.w * scale;

        y4[ridx] = ep;
        float4 o;
        if (first) {
            o.x = ep.x * invL; o.y = ep.y * invL; o.z = ep.z * invL; o.w = ep.w * invL;
        } else {
            float4 po = o4[ridx];
            o.x = fmaf(ep.x, invL, po.x); o.y = fmaf(ep.y, invL, po.y);
            o.z = fmaf(ep.z, invL, po.z); o.w = fmaf(ep.w, invL, po.w);
        }
        o4[ridx] = o;
    }
}

// ---------------- fallback path (round-1 kernels) ----------------
__global__ void spmm_kernel(const int* __restrict__ row, const int* __restrict__ col,
                            const float* __restrict__ val, const float* __restrict__ x,
                            float* __restrict__ y, int nnz) {
    int gtid = blockIdx.x * blockDim.x + threadIdx.x;
    int wid = gtid >> 6;
    int lane = threadIdx.x & 63;
    int nwaves = (gridDim.x * blockDim.x) >> 6;
    for (int e = wid; e < nnz; e += nwaves) {
        int r = row[e];
        int c = col[e];
        float v = val[e];
        unsafeAtomicAdd(&y[(size_t)r * DDIM + lane], v * x[(size_t)c * DDIM + lane]);
    }
}

__global__ void perturb_kernel(float* __restrict__ ego, const float* __restrict__ noise,
                               float* __restrict__ zero_buf, float* __restrict__ out,
                               int N, int first, float invL) {
    int gtid = blockIdx.x * blockDim.x + threadIdx.x;
    int wid = gtid >> 6;
    int lane = threadIdx.x & 63;
    int nwaves = (gridDim.x * blockDim.x) >> 6;
    for (int n = wid; n < N; n += nwaves) {
        size_t idx = (size_t)n * DDIM + lane;
        float nv = noise[idx];
        float sq = nv * nv;
        #pragma unroll
        for (int off = 32; off > 0; off >>= 1) sq += __shfl_xor(sq, off, 64);
        float rn = nv / fmaxf(sqrtf(sq), NORM_EPS);
        float e = ego[idx];
        float s = (e > 0.0f) ? 1.0f : ((e < 0.0f) ? -1.0f : 0.0f);
        float ep = e + s * rn * EPS;
        ego[idx] = ep;
        if (zero_buf) zero_buf[idx] = 0.0f;
        float o = ep * invL;
        out[idx] = first ? o : (out[idx] + o);
    }
}

extern "C" void kernel_launch(void* const* d_in, const int* in_sizes, int n_in,
                              void* d_out, int out_size, void* d_ws, size_t ws_size,
                              hipStream_t stream) {
    const float* user  = (const float*)d_in[0];
    const float* item  = (const float*)d_in[1];
    const int*   row   = (const int*)d_in[2];
    const int*   col   = (const int*)d_in[3];
    const float* val   = (const float*)d_in[4];
    const float* noise = (const float*)d_in[5];
    float* out = (float*)d_out;

    int UD = in_sizes[0];
    int ID = in_sizes[1];
    int ND = UD + ID;
    int N  = ND / DDIM;
    int nnz = in_sizes[2];
    int L  = in_sizes[5] / ND;
    float invL = 1.0f / (float)L;

    // ws layout (4B units): egoA(ND)|egoB(ND)|rowptr(N+2)|cnt(N)|partial(N)|bsums(1024)|pos(nnz)|edges(2*nnz)
    size_t ND_ = (size_t)ND;
    size_t ofs_rowptr  = 2 * ND_;
    size_t ofs_cnt     = ofs_rowptr + (size_t)(N + 2);
    size_t ofs_partial = ofs_cnt + (size_t)N;
    size_t ofs_bsums   = ofs_partial + (size_t)N;
    size_t ofs_pos     = ofs_bsums + 1024;
    size_t ofs_edges   = ofs_pos + (size_t)nnz;
    size_t needed = (ofs_edges + 2ull * (size_t)nnz) * 4ull;

    float* egoA = (float*)d_ws;
    float* egoB = egoA + ND_;

    if (ws_size >= needed && (N % 2) == 0 && (nnz % 2) == 0) {
        int* rowptr  = (int*)d_ws + ofs_rowptr;
        int* cnt     = (int*)d_ws + ofs_cnt;
        int* partial = (int*)d_ws + ofs_partial;
        int* bsums   = (int*)d_ws + ofs_bsums;
        int* pos     = (int*)d_ws + ofs_pos;
        int2* edges  = (int2*)((int*)d_ws + ofs_edges);

        int nb = (N + 1023) / 1024;

        init_kernel<<<(ND + 255) / 256, 256, 0, stream>>>(user, item, egoA, UD, ND);
        zero_int_kernel<<<(N + 255) / 256, 256, 0, stream>>>(cnt, N);
        hist_kernel<<<(nnz + 255) / 256, 256, 0, stream>>>(row, cnt, pos, nnz);
        scan1_kernel<<<nb, 1024, 0, stream>>>(cnt, partial, bsums, N);
        scan2_kernel<<<1, 64, 0, stream>>>(bsums, nb);
        scan3_kernel<<<nb, 1024, 0, stream>>>(partial, bsums, rowptr, N);
        scatter_kernel<<<(nnz + 255) / 256, 256, 0, stream>>>(row, col, val, rowptr, pos, edges, nnz);

        float* cur = egoA;
        float* nxt = egoB;
        int blocks = (N * 64 + 255) / 256;
        for (int k = 0; k < L; ++k) {
            fused_layer_kernel<<<blocks, 256, 0, stream>>>(
                rowptr, edges, cur, noise + (size_t)k * ND_, nxt, out,
                N, (k == 0) ? 1 : 0, invL);
            float* t = cur; cur = nxt; nxt = t;
        }
    } else {
        // fallback: round-1 atomic path
        init_zero_kernel<<<(ND + 255) / 256, 256, 0, stream>>>(user, item, egoA, egoB, UD, ND);
        float* cur = egoA;
        float* nxt = egoB;
        for (int k = 0; k < L; ++k) {
            spmm_kernel<<<2048, 256, 0, stream>>>(row, col, val, cur, nxt, nnz);
            perturb_kernel<<<1024, 256, 0, stream>>>(
                nxt, noise + (size_t)k * ND_,
                (k + 1 < L) ? cur : nullptr, out, N, (k == 0) ? 1 : 0, invL);
            float* t = cur; cur = nxt; nxt = t;
        }
    }
}

// Round 4
// 451.773 us; speedup vs baseline: 3.1679x; 1.0897x over previous
//
#include <hip/hip_runtime.h>

#define DDIM 64
#define EPS 0.1f
#define NORM_EPS 1e-12f

// ---------------- fallback init ----------------
__global__ void init_zero_kernel(const float* __restrict__ user, const float* __restrict__ item,
                                 float* __restrict__ egoA, float* __restrict__ egoB,
                                 int UD, int ND) {
    int i = blockIdx.x * blockDim.x + threadIdx.x;
    if (i < ND) {
        egoA[i] = (i < UD) ? user[i] : item[i - UD];
        egoB[i] = 0.0f;
    }
}

// ---------------- CSR build ----------------
__global__ void zero_int_kernel(int* __restrict__ p, int n) {
    int i = blockIdx.x * blockDim.x + threadIdx.x;
    if (i < n) p[i] = 0;
}

// histogram + per-edge position within its row
__global__ void hist_kernel(const int* __restrict__ row, int* __restrict__ cnt,
                            int* __restrict__ pos, int nnz) {
    int e = blockIdx.x * blockDim.x + threadIdx.x;
    if (e < nnz) pos[e] = atomicAdd(&cnt[row[e]], 1);
}

// block-wise inclusive scan (1024/block) + block sums
__global__ void scan1_kernel(const int* __restrict__ cnt, int* __restrict__ partial,
                             int* __restrict__ bsums, int n) {
    __shared__ int s[1024];
    int i = blockIdx.x * 1024 + threadIdx.x;
    int v = (i < n) ? cnt[i] : 0;
    s[threadIdx.x] = v;
    __syncthreads();
    for (int off = 1; off < 1024; off <<= 1) {
        int t = (threadIdx.x >= off) ? s[threadIdx.x - off] : 0;
        __syncthreads();
        s[threadIdx.x] += t;
        __syncthreads();
    }
    if (i < n) partial[i] = s[threadIdx.x];
    if (threadIdx.x == 1023) bsums[blockIdx.x] = s[1023];
}

// serial fallback scan of block sums (only used if nb > 1024)
__global__ void scan2_kernel(int* __restrict__ bsums, int nb) {
    if (blockIdx.x == 0 && threadIdx.x == 0) {
        int run = 0;
        for (int b = 0; b < nb; ++b) { int t = bsums[b]; bsums[b] = run; run += t; }
    }
}

__global__ void scan3_serialbs_kernel(const int* __restrict__ partial, const int* __restrict__ bsums,
                                      int* __restrict__ rowptr, int n) {
    int i = blockIdx.x * 1024 + threadIdx.x;
    if (i < n) rowptr[i + 1] = partial[i] + bsums[blockIdx.x];
    if (i == 0) rowptr[0] = 0;
}

// fused: each block computes its own exclusive prefix over bsums (nb <= 1024)
__global__ void scan3_fused_kernel(const int* __restrict__ partial, const int* __restrict__ bsums,
                                   int* __restrict__ rowptr, int n, int nb) {
    __shared__ int s[1024];
    int t = threadIdx.x;
    s[t] = (t < nb && t < (int)blockIdx.x) ? bsums[t] : 0;
    __syncthreads();
    #pragma unroll
    for (int off = 512; off > 0; off >>= 1) {
        if (t < off) s[t] += s[t + off];
        __syncthreads();
    }
    int base = s[0];
    int i = blockIdx.x * 1024 + t;
    if (i < n) rowptr[i + 1] = partial[i] + base;
    if (i == 0) rowptr[0] = 0;
}

__global__ void scatter_kernel(const int* __restrict__ row, const int* __restrict__ col,
                               const float* __restrict__ val, const int* __restrict__ rowptr,
                               const int* __restrict__ pos, int2* __restrict__ edges, int nnz) {
    int e = blockIdx.x * blockDim.x + threadIdx.x;
    if (e < nnz) {
        int r = row[e];
        edges[rowptr[r] + pos[e]] = make_int2(col[e], __float_as_int(val[e]));
    }
}

// ---------------- fused layer: CSR spmm + perturb + out accumulate ----------------
// one wave per output row; 4 x 16-lane groups; 16 edges in flight per iteration.
// x source: row4 < split4 ? xa4[row4] : xb4[row4-split4]  (layer 0 reads user/item directly)
__global__ void fused_layer_kernel(const int* __restrict__ rowptr, const int2* __restrict__ edges,
                                   const float4* __restrict__ xa4, const float4* __restrict__ xb4,
                                   int split4,
                                   const float4* __restrict__ noise4,
                                   float4* __restrict__ y4, float4* __restrict__ out4,
                                   int N, int first, float invL) {
    int lane = threadIdx.x & 63;
    int r = (blockIdx.x * blockDim.x + threadIdx.x) >> 6;
    if (r >= N) return;
    int g   = lane >> 4;   // edge group 0..3
    int sub = lane & 15;   // float4 index within row

    size_t ridx = (size_t)r * 16 + sub;

    // issue epilogue loads early (overlap with gather)
    float4 nv = make_float4(0.f, 0.f, 0.f, 0.f);
    float4 po = make_float4(0.f, 0.f, 0.f, 0.f);
    if (g == 0) {
        nv = noise4[ridx];
        if (!first) po = out4[ridx];
    }

    int beg = __builtin_amdgcn_readfirstlane(rowptr[r]);
    int end = __builtin_amdgcn_readfirstlane(rowptr[r + 1]);

    float4 a0 = make_float4(0.f, 0.f, 0.f, 0.f);
    float4 a1 = make_float4(0.f, 0.f, 0.f, 0.f);
    float4 a2 = make_float4(0.f, 0.f, 0.f, 0.f);
    float4 a3 = make_float4(0.f, 0.f, 0.f, 0.f);

    for (int e = beg; e < end; e += 16) {
        int last = end - 1;
        // quad 0 always has >=1 active edge
        {
            int ee = e + g;
            int2 ed = edges[min(ee, last)];
            float v = (ee < end) ? __int_as_float(ed.y) : 0.0f;
            int row4 = ed.x * 16 + sub;
            float4 xv = (row4 < split4) ? xa4[row4] : xb4[row4 - split4];
            a0.x = fmaf(v, xv.x, a0.x); a0.y = fmaf(v, xv.y, a0.y);
            a0.z = fmaf(v, xv.z, a0.z); a0.w = fmaf(v, xv.w, a0.w);
        }
        if (e + 4 < end) {
            int ee = e + 4 + g;
            int2 ed = edges[min(ee, last)];
            float v = (ee < end) ? __int_as_float(ed.y) : 0.0f;
            int row4 = ed.x * 16 + sub;
            float4 xv = (row4 < split4) ? xa4[row4] : xb4[row4 - split4];
            a1.x = fmaf(v, xv.x, a1.x); a1.y = fmaf(v, xv.y, a1.y);
            a1.z = fmaf(v, xv.z, a1.z); a1.w = fmaf(v, xv.w, a1.w);
        }
        if (e + 8 < end) {
            int ee = e + 8 + g;
            int2 ed = edges[min(ee, last)];
            float v = (ee < end) ? __int_as_float(ed.y) : 0.0f;
            int row4 = ed.x * 16 + sub;
            float4 xv = (row4 < split4) ? xa4[row4] : xb4[row4 - split4];
            a2.x = fmaf(v, xv.x, a2.x); a2.y = fmaf(v, xv.y, a2.y);
            a2.z = fmaf(v, xv.z, a2.z); a2.w = fmaf(v, xv.w, a2.w);
        }
        if (e + 12 < end) {
            int ee = e + 12 + g;
            int2 ed = edges[min(ee, last)];
            float v = (ee < end) ? __int_as_float(ed.y) : 0.0f;
            int row4 = ed.x * 16 + sub;
            float4 xv = (row4 < split4) ? xa4[row4] : xb4[row4 - split4];
            a3.x = fmaf(v, xv.x, a3.x); a3.y = fmaf(v, xv.y, a3.y);
            a3.z = fmaf(v, xv.z, a3.z); a3.w = fmaf(v, xv.w, a3.w);
        }
    }

    float4 acc;
    acc.x = (a0.x + a1.x) + (a2.x + a3.x);
    acc.y = (a0.y + a1.y) + (a2.y + a3.y);
    acc.z = (a0.z + a1.z) + (a2.z + a3.z);
    acc.w = (a0.w + a1.w) + (a2.w + a3.w);

    // cross-group reduce: lanes {sub, sub+16, sub+32, sub+48} sum up
    #pragma unroll
    for (int off = 16; off <= 32; off <<= 1) {
        acc.x += __shfl_xor(acc.x, off, 64);
        acc.y += __shfl_xor(acc.y, off, 64);
        acc.z += __shfl_xor(acc.z, off, 64);
        acc.w += __shfl_xor(acc.w, off, 64);
    }

    // epilogue in group 0 only (16 lanes x float4 = full 64-dim row)
    if (g == 0) {
        float sq = nv.x * nv.x + nv.y * nv.y + nv.z * nv.z + nv.w * nv.w;
        #pragma unroll
        for (int off = 1; off <= 8; off <<= 1) sq += __shfl_xor(sq, off, 64);
        float scale = EPS / fmaxf(sqrtf(sq), NORM_EPS);

        float4 ep;
        float s;
        s = (acc.x > 0.f) ? 1.f : ((acc.x < 0.f) ? -1.f : 0.f); ep.x = acc.x + s * nv.x * scale;
        s = (acc.y > 0.f) ? 1.f : ((acc.y < 0.f) ? -1.f : 0.f); ep.y = acc.y + s * nv.y * scale;
        s = (acc.z > 0.f) ? 1.f : ((acc.z < 0.f) ? -1.f : 0.f); ep.z = acc.z + s * nv.z * scale;
        s = (acc.w > 0.f) ? 1.f : ((acc.w < 0.f) ? -1.f : 0.f); ep.w = acc.w + s * nv.w * scale;

        if (y4) y4[ridx] = ep;
        float4 o;
        if (first) {
            o.x = ep.x * invL; o.y = ep.y * invL; o.z = ep.z * invL; o.w = ep.w * invL;
        } else {
            o.x = fmaf(ep.x, invL, po.x); o.y = fmaf(ep.y, invL, po.y);
            o.z = fmaf(ep.z, invL, po.z); o.w = fmaf(ep.w, invL, po.w);
        }
        out4[ridx] = o;
    }
}

// ---------------- fallback path (round-1 kernels) ----------------
__global__ void spmm_kernel(const int* __restrict__ row, const int* __restrict__ col,
                            const float* __restrict__ val, const float* __restrict__ x,
                            float* __restrict__ y, int nnz) {
    int gtid = blockIdx.x * blockDim.x + threadIdx.x;
    int wid = gtid >> 6;
    int lane = threadIdx.x & 63;
    int nwaves = (gridDim.x * blockDim.x) >> 6;
    for (int e = wid; e < nnz; e += nwaves) {
        int r = row[e];
        int c = col[e];
        float v = val[e];
        unsafeAtomicAdd(&y[(size_t)r * DDIM + lane], v * x[(size_t)c * DDIM + lane]);
    }
}

__global__ void perturb_kernel(float* __restrict__ ego, const float* __restrict__ noise,
                               float* __restrict__ zero_buf, float* __restrict__ out,
                               int N, int first, float invL) {
    int gtid = blockIdx.x * blockDim.x + threadIdx.x;
    int wid = gtid >> 6;
    int lane = threadIdx.x & 63;
    int nwaves = (gridDim.x * blockDim.x) >> 6;
    for (int n = wid; n < N; n += nwaves) {
        size_t idx = (size_t)n * DDIM + lane;
        float nv = noise[idx];
        float sq = nv * nv;
        #pragma unroll
        for (int off = 32; off > 0; off >>= 1) sq += __shfl_xor(sq, off, 64);
        float rn = nv / fmaxf(sqrtf(sq), NORM_EPS);
        float e = ego[idx];
        float s = (e > 0.0f) ? 1.0f : ((e < 0.0f) ? -1.0f : 0.0f);
        float ep = e + s * rn * EPS;
        ego[idx] = ep;
        if (zero_buf) zero_buf[idx] = 0.0f;
        float o = ep * invL;
        out[idx] = first ? o : (out[idx] + o);
    }
}

extern "C" void kernel_launch(void* const* d_in, const int* in_sizes, int n_in,
                              void* d_out, int out_size, void* d_ws, size_t ws_size,
                              hipStream_t stream) {
    const float* user  = (const float*)d_in[0];
    const float* item  = (const float*)d_in[1];
    const int*   row   = (const int*)d_in[2];
    const int*   col   = (const int*)d_in[3];
    const float* val   = (const float*)d_in[4];
    const float* noise = (const float*)d_in[5];
    float* out = (float*)d_out;

    int UD = in_sizes[0];
    int ID = in_sizes[1];
    int ND = UD + ID;
    int N  = ND / DDIM;
    int nnz = in_sizes[2];
    int L  = in_sizes[5] / ND;
    float invL = 1.0f / (float)L;

    // ws layout (4B units): egoA(ND)|egoB(ND)|rowptr(N+2)|cnt(N)|partial(N)|bsums(1024)|pos(nnz)|edges(2*nnz)
    size_t ND_ = (size_t)ND;
    size_t ofs_rowptr  = 2 * ND_;
    size_t ofs_cnt     = ofs_rowptr + (size_t)(N + 2);
    size_t ofs_partial = ofs_cnt + (size_t)N;
    size_t ofs_bsums   = ofs_partial + (size_t)N;
    size_t ofs_pos     = ofs_bsums + 1024;
    size_t ofs_edges   = ofs_pos + (size_t)nnz;
    size_t needed = (ofs_edges + 2ull * (size_t)nnz) * 4ull;

    float* egoA = (float*)d_ws;
    float* egoB = egoA + ND_;

    if (ws_size >= needed && (N % 2) == 0 && (nnz % 2) == 0 && (UD % 64) == 0) {
        int* rowptr  = (int*)d_ws + ofs_rowptr;
        int* cnt     = (int*)d_ws + ofs_cnt;
        int* partial = (int*)d_ws + ofs_partial;
        int* bsums   = (int*)d_ws + ofs_bsums;
        int* pos     = (int*)d_ws + ofs_pos;
        int2* edges  = (int2*)((int*)d_ws + ofs_edges);

        int nb = (N + 1023) / 1024;

        zero_int_kernel<<<(N + 255) / 256, 256, 0, stream>>>(cnt, N);
        hist_kernel<<<(nnz + 255) / 256, 256, 0, stream>>>(row, cnt, pos, nnz);
        scan1_kernel<<<nb, 1024, 0, stream>>>(cnt, partial, bsums, N);
        if (nb <= 1024) {
            scan3_fused_kernel<<<nb, 1024, 0, stream>>>(partial, bsums, rowptr, N, nb);
        } else {
            scan2_kernel<<<1, 64, 0, stream>>>(bsums, nb);
            scan3_serialbs_kernel<<<nb, 1024, 0, stream>>>(partial, bsums, rowptr, N);
        }
        scatter_kernel<<<(nnz + 255) / 256, 256, 0, stream>>>(row, col, val, rowptr, pos, edges, nnz);

        const float4* user4 = (const float4*)user;
        const float4* item4 = (const float4*)item;
        float4* egoA4 = (float4*)egoA;
        float4* egoB4 = (float4*)egoB;
        const float4* noise4 = (const float4*)noise;
        float4* out4 = (float4*)out;
        int splitUD4 = UD / 4;           // float4 units in user block
        const int BIG = 0x7FFFFFFF;

        int blocks = (N * 64 + 255) / 256;
        float4* bufs[2] = { egoB4, egoA4 };
        for (int k = 0; k < L; ++k) {
            const float4* xa = (k == 0) ? user4 : (const float4*)bufs[(k - 1) & 1];
            const float4* xb = (k == 0) ? item4 : (const float4*)bufs[(k - 1) & 1];
            int split4 = (k == 0) ? splitUD4 : BIG;
            float4* y = (k == L - 1) ? nullptr : bufs[k & 1];
            fused_layer_kernel<<<blocks, 256, 0, stream>>>(
                rowptr, edges, xa, xb, split4,
                noise4 + (size_t)k * (ND_ / 4), y, out4,
                N, (k == 0) ? 1 : 0, invL);
        }
    } else {
        // fallback: round-1 atomic path
        init_zero_kernel<<<(ND + 255) / 256, 256, 0, stream>>>(user, item, egoA, egoB, UD, ND);
        float* cur = egoA;
        float* nxt = egoB;
        for (int k = 0; k < L; ++k) {
            spmm_kernel<<<2048, 256, 0, stream>>>(row, col, val, cur, nxt, nnz);
            perturb_kernel<<<1024, 256, 0, stream>>>(
                nxt, noise + (size_t)k * ND_,
                (k + 1 < L) ? cur : nullptr, out, N, (k == 0) ? 1 : 0, invL);
            float* t = cur; cur = nxt; nxt = t;
        }
    }
}

// Round 5
// 375.918 us; speedup vs baseline: 3.8071x; 1.2018x over previous
//
#include <hip/hip_runtime.h>
#include <hip/hip_fp16.h>

#define DDIM 64
#define EPS 0.1f
#define NORM_EPS 1e-12f

// ---------------- fallback init ----------------
__global__ void init_zero_kernel(const float* __restrict__ user, const float* __restrict__ item,
                                 float* __restrict__ egoA, float* __restrict__ egoB,
                                 int UD, int ND) {
    int i = blockIdx.x * blockDim.x + threadIdx.x;
    if (i < ND) {
        egoA[i] = (i < UD) ? user[i] : item[i - UD];
        egoB[i] = 0.0f;
    }
}

// ---------------- CSR build ----------------
__global__ void zero_int_kernel(int* __restrict__ p, int n) {
    int i = blockIdx.x * blockDim.x + threadIdx.x;
    if (i < n) p[i] = 0;
}

__global__ void hist_kernel(const int* __restrict__ row, int* __restrict__ cnt,
                            int* __restrict__ pos, int nnz) {
    int e = blockIdx.x * blockDim.x + threadIdx.x;
    if (e < nnz) pos[e] = atomicAdd(&cnt[row[e]], 1);
}

__global__ void scan1_kernel(const int* __restrict__ cnt, int* __restrict__ partial,
                             int* __restrict__ bsums, int n) {
    __shared__ int s[1024];
    int i = blockIdx.x * 1024 + threadIdx.x;
    int v = (i < n) ? cnt[i] : 0;
    s[threadIdx.x] = v;
    __syncthreads();
    for (int off = 1; off < 1024; off <<= 1) {
        int t = (threadIdx.x >= off) ? s[threadIdx.x - off] : 0;
        __syncthreads();
        s[threadIdx.x] += t;
        __syncthreads();
    }
    if (i < n) partial[i] = s[threadIdx.x];
    if (threadIdx.x == 1023) bsums[blockIdx.x] = s[1023];
}

__global__ void scan2_kernel(int* __restrict__ bsums, int nb) {
    if (blockIdx.x == 0 && threadIdx.x == 0) {
        int run = 0;
        for (int b = 0; b < nb; ++b) { int t = bsums[b]; bsums[b] = run; run += t; }
    }
}

__global__ void scan3_serialbs_kernel(const int* __restrict__ partial, const int* __restrict__ bsums,
                                      int* __restrict__ rowptr, int n) {
    int i = blockIdx.x * 1024 + threadIdx.x;
    if (i < n) rowptr[i + 1] = partial[i] + bsums[blockIdx.x];
    if (i == 0) rowptr[0] = 0;
}

__global__ void scan3_fused_kernel(const int* __restrict__ partial, const int* __restrict__ bsums,
                                   int* __restrict__ rowptr, int n, int nb) {
    __shared__ int s[1024];
    int t = threadIdx.x;
    s[t] = (t < nb && t < (int)blockIdx.x) ? bsums[t] : 0;
    __syncthreads();
    #pragma unroll
    for (int off = 512; off > 0; off >>= 1) {
        if (t < off) s[t] += s[t + off];
        __syncthreads();
    }
    int base = s[0];
    int i = blockIdx.x * 1024 + t;
    if (i < n) rowptr[i + 1] = partial[i] + base;
    if (i == 0) rowptr[0] = 0;
}

__global__ void scatter_kernel(const int* __restrict__ row, const int* __restrict__ col,
                               const float* __restrict__ val, const int* __restrict__ rowptr,
                               const int* __restrict__ pos, int2* __restrict__ edges, int nnz) {
    int e = blockIdx.x * blockDim.x + threadIdx.x;
    if (e < nnz) {
        int r = row[e];
        edges[rowptr[r] + pos[e]] = make_int2(col[e], __float_as_int(val[e]));
    }
}

// ---------------- fused layer ----------------
__device__ __forceinline__ void acc_half8(float f[8], const uint4& q, float v) {
    __half2 h; float2 t;
    h = *reinterpret_cast<const __half2*>(&q.x); t = __half22float2(h);
    f[0] = fmaf(v, t.x, f[0]); f[1] = fmaf(v, t.y, f[1]);
    h = *reinterpret_cast<const __half2*>(&q.y); t = __half22float2(h);
    f[2] = fmaf(v, t.x, f[2]); f[3] = fmaf(v, t.y, f[3]);
    h = *reinterpret_cast<const __half2*>(&q.z); t = __half22float2(h);
    f[4] = fmaf(v, t.x, f[4]); f[5] = fmaf(v, t.y, f[5]);
    h = *reinterpret_cast<const __half2*>(&q.w); t = __half22float2(h);
    f[6] = fmaf(v, t.x, f[6]); f[7] = fmaf(v, t.y, f[7]);
}

// one wave per output row; 8 groups x 8 lanes; 16 edges in flight per iteration.
// XHALF=0: gather fp32 from user/item (layer 0).  XHALF=1: gather fp16 ego.
template <int XHALF>
__global__ void fused_layer_kernel(const int* __restrict__ rowptr, const int2* __restrict__ edges,
                                   const float4* __restrict__ xu4, const float4* __restrict__ xi4,
                                   int splitRow,
                                   const uint4* __restrict__ x16,
                                   const float4* __restrict__ noise4,
                                   uint4* __restrict__ y16, float4* __restrict__ out4,
                                   int N, int first, float invL) {
    int lane = threadIdx.x & 63;
    int r = (blockIdx.x * blockDim.x + threadIdx.x) >> 6;
    if (r >= N) return;
    int g   = lane >> 3;   // edge group 0..7
    int sub = lane & 7;    // 8-dim chunk within row

    // issue epilogue loads early (group 0 only)
    float4 nva = make_float4(0.f,0.f,0.f,0.f), nvb = make_float4(0.f,0.f,0.f,0.f);
    float4 poa = make_float4(0.f,0.f,0.f,0.f), pob = make_float4(0.f,0.f,0.f,0.f);
    size_t f4idx = (size_t)r * 16 + sub * 2;
    if (g == 0) {
        nva = noise4[f4idx]; nvb = noise4[f4idx + 1];
        if (!first) { poa = out4[f4idx]; pob = out4[f4idx + 1]; }
    }

    int beg = __builtin_amdgcn_readfirstlane(rowptr[r]);
    int end = __builtin_amdgcn_readfirstlane(rowptr[r + 1]);

    float f[8] = {0.f,0.f,0.f,0.f,0.f,0.f,0.f,0.f};

    for (int e = beg; e < end; e += 16) {
        int last = end - 1;
        int e0 = e + g, e1 = e + 8 + g;
        int2 ed0 = edges[min(e0, last)];
        int2 ed1 = edges[min(e1, last)];
        float v0 = (e0 < end) ? __int_as_float(ed0.y) : 0.0f;
        float v1 = (e1 < end) ? __int_as_float(ed1.y) : 0.0f;
        if (XHALF) {
            uint4 q0 = x16[(size_t)ed0.x * 8 + sub];
            uint4 q1 = x16[(size_t)ed1.x * 8 + sub];
            acc_half8(f, q0, v0);
            acc_half8(f, q1, v1);
        } else {
            const float4* s0 = (ed0.x < splitRow) ? (xu4 + (size_t)ed0.x * 16)
                                                  : (xi4 + (size_t)(ed0.x - splitRow) * 16);
            const float4* s1 = (ed1.x < splitRow) ? (xu4 + (size_t)ed1.x * 16)
                                                  : (xi4 + (size_t)(ed1.x - splitRow) * 16);
            float4 a0 = s0[sub * 2], b0 = s0[sub * 2 + 1];
            float4 a1 = s1[sub * 2], b1 = s1[sub * 2 + 1];
            f[0]=fmaf(v0,a0.x,f[0]); f[1]=fmaf(v0,a0.y,f[1]); f[2]=fmaf(v0,a0.z,f[2]); f[3]=fmaf(v0,a0.w,f[3]);
            f[4]=fmaf(v0,b0.x,f[4]); f[5]=fmaf(v0,b0.y,f[5]); f[6]=fmaf(v0,b0.z,f[6]); f[7]=fmaf(v0,b0.w,f[7]);
            f[0]=fmaf(v1,a1.x,f[0]); f[1]=fmaf(v1,a1.y,f[1]); f[2]=fmaf(v1,a1.z,f[2]); f[3]=fmaf(v1,a1.w,f[3]);
            f[4]=fmaf(v1,b1.x,f[4]); f[5]=fmaf(v1,b1.y,f[5]); f[6]=fmaf(v1,b1.z,f[6]); f[7]=fmaf(v1,b1.w,f[7]);
        }
    }

    // cross-group reduce: lanes differing in bits 3..5 sum up
    #pragma unroll
    for (int off = 8; off <= 32; off <<= 1) {
        #pragma unroll
        for (int i = 0; i < 8; ++i) f[i] += __shfl_xor(f[i], off, 64);
    }

    // epilogue in group 0 (8 lanes x 8 dims = full row)
    if (g == 0) {
        float sq = nva.x*nva.x + nva.y*nva.y + nva.z*nva.z + nva.w*nva.w
                 + nvb.x*nvb.x + nvb.y*nvb.y + nvb.z*nvb.z + nvb.w*nvb.w;
        #pragma unroll
        for (int off = 1; off <= 4; off <<= 1) sq += __shfl_xor(sq, off, 64);
        float scale = EPS / fmaxf(sqrtf(sq), NORM_EPS);

        float nse[8] = {nva.x,nva.y,nva.z,nva.w,nvb.x,nvb.y,nvb.z,nvb.w};
        float po[8]  = {poa.x,poa.y,poa.z,poa.w,pob.x,pob.y,pob.z,pob.w};
        float ep[8];
        #pragma unroll
        for (int i = 0; i < 8; ++i) {
            float s = (f[i] > 0.f) ? 1.f : ((f[i] < 0.f) ? -1.f : 0.f);
            ep[i] = f[i] + s * nse[i] * scale;
        }
        if (y16) {
            __half2 h0 = __floats2half2_rn(ep[0], ep[1]);
            __half2 h1 = __floats2half2_rn(ep[2], ep[3]);
            __half2 h2 = __floats2half2_rn(ep[4], ep[5]);
            __half2 h3 = __floats2half2_rn(ep[6], ep[7]);
            uint4 st;
            st.x = *reinterpret_cast<unsigned*>(&h0);
            st.y = *reinterpret_cast<unsigned*>(&h1);
            st.z = *reinterpret_cast<unsigned*>(&h2);
            st.w = *reinterpret_cast<unsigned*>(&h3);
            y16[(size_t)r * 8 + sub] = st;
        }
        float4 oa, ob;
        if (first) {
            oa = make_float4(ep[0]*invL, ep[1]*invL, ep[2]*invL, ep[3]*invL);
            ob = make_float4(ep[4]*invL, ep[5]*invL, ep[6]*invL, ep[7]*invL);
        } else {
            oa = make_float4(fmaf(ep[0],invL,po[0]), fmaf(ep[1],invL,po[1]),
                             fmaf(ep[2],invL,po[2]), fmaf(ep[3],invL,po[3]));
            ob = make_float4(fmaf(ep[4],invL,po[4]), fmaf(ep[5],invL,po[5]),
                             fmaf(ep[6],invL,po[6]), fmaf(ep[7],invL,po[7]));
        }
        out4[f4idx] = oa;
        out4[f4idx + 1] = ob;
    }
}

// ---------------- fallback path (round-1 kernels) ----------------
__global__ void spmm_kernel(const int* __restrict__ row, const int* __restrict__ col,
                            const float* __restrict__ val, const float* __restrict__ x,
                            float* __restrict__ y, int nnz) {
    int gtid = blockIdx.x * blockDim.x + threadIdx.x;
    int wid = gtid >> 6;
    int lane = threadIdx.x & 63;
    int nwaves = (gridDim.x * blockDim.x) >> 6;
    for (int e = wid; e < nnz; e += nwaves) {
        int r = row[e];
        int c = col[e];
        float v = val[e];
        unsafeAtomicAdd(&y[(size_t)r * DDIM + lane], v * x[(size_t)c * DDIM + lane]);
    }
}

__global__ void perturb_kernel(float* __restrict__ ego, const float* __restrict__ noise,
                               float* __restrict__ zero_buf, float* __restrict__ out,
                               int N, int first, float invL) {
    int gtid = blockIdx.x * blockDim.x + threadIdx.x;
    int wid = gtid >> 6;
    int lane = threadIdx.x & 63;
    int nwaves = (gridDim.x * blockDim.x) >> 6;
    for (int n = wid; n < N; n += nwaves) {
        size_t idx = (size_t)n * DDIM + lane;
        float nv = noise[idx];
        float sq = nv * nv;
        #pragma unroll
        for (int off = 32; off > 0; off >>= 1) sq += __shfl_xor(sq, off, 64);
        float rn = nv / fmaxf(sqrtf(sq), NORM_EPS);
        float e = ego[idx];
        float s = (e > 0.0f) ? 1.0f : ((e < 0.0f) ? -1.0f : 0.0f);
        float ep = e + s * rn * EPS;
        ego[idx] = ep;
        if (zero_buf) zero_buf[idx] = 0.0f;
        float o = ep * invL;
        out[idx] = first ? o : (out[idx] + o);
    }
}

extern "C" void kernel_launch(void* const* d_in, const int* in_sizes, int n_in,
                              void* d_out, int out_size, void* d_ws, size_t ws_size,
                              hipStream_t stream) {
    const float* user  = (const float*)d_in[0];
    const float* item  = (const float*)d_in[1];
    const int*   row   = (const int*)d_in[2];
    const int*   col   = (const int*)d_in[3];
    const float* val   = (const float*)d_in[4];
    const float* noise = (const float*)d_in[5];
    float* out = (float*)d_out;

    int UD = in_sizes[0];
    int ID = in_sizes[1];
    int ND = UD + ID;
    int N  = ND / DDIM;
    int nnz = in_sizes[2];
    int L  = in_sizes[5] / ND;
    float invL = 1.0f / (float)L;

    // ws layout (4B units):
    // ego16A(ND/2) | ego16B(ND/2) | rowptr(N+2) | cnt(N) | partial(N) | bsums(1024) | pos(nnz) | edges(2*nnz)
    size_t ND_ = (size_t)ND;
    size_t ofs_rowptr  = ND_;
    size_t ofs_cnt     = ofs_rowptr + (size_t)(N + 2);
    size_t ofs_partial = ofs_cnt + (size_t)N;
    size_t ofs_bsums   = ofs_partial + (size_t)N;
    size_t ofs_pos     = ofs_bsums + 1024;
    size_t ofs_edges   = ofs_pos + (size_t)nnz;
    size_t needed = (ofs_edges + 2ull * (size_t)nnz) * 4ull;

    if (ws_size >= needed && (N % 2) == 0 && (nnz % 2) == 0 && (UD % DDIM) == 0) {
        uint4* ego16A = (uint4*)d_ws;
        uint4* ego16B = (uint4*)((char*)d_ws + 2ull * ND_);   // ND/2 floats = 2*ND bytes
        int* rowptr  = (int*)d_ws + ofs_rowptr;
        int* cnt     = (int*)d_ws + ofs_cnt;
        int* partial = (int*)d_ws + ofs_partial;
        int* bsums   = (int*)d_ws + ofs_bsums;
        int* pos     = (int*)d_ws + ofs_pos;
        int2* edges  = (int2*)((int*)d_ws + ofs_edges);

        int nb = (N + 1023) / 1024;

        zero_int_kernel<<<(N + 255) / 256, 256, 0, stream>>>(cnt, N);
        hist_kernel<<<(nnz + 255) / 256, 256, 0, stream>>>(row, cnt, pos, nnz);
        scan1_kernel<<<nb, 1024, 0, stream>>>(cnt, partial, bsums, N);
        if (nb <= 1024) {
            scan3_fused_kernel<<<nb, 1024, 0, stream>>>(partial, bsums, rowptr, N, nb);
        } else {
            scan2_kernel<<<1, 64, 0, stream>>>(bsums, nb);
            scan3_serialbs_kernel<<<nb, 1024, 0, stream>>>(partial, bsums, rowptr, N);
        }
        scatter_kernel<<<(nnz + 255) / 256, 256, 0, stream>>>(row, col, val, rowptr, pos, edges, nnz);

        const float4* user4 = (const float4*)user;
        const float4* item4 = (const float4*)item;
        const float4* noise4 = (const float4*)noise;
        float4* out4 = (float4*)out;
        int Urows = UD / DDIM;

        int blocks = (N * 64 + 255) / 256;
        uint4* e16[2] = { ego16A, ego16B };
        for (int k = 0; k < L; ++k) {
            uint4* y = (k == L - 1) ? nullptr : e16[k & 1];
            const float4* nz = noise4 + (size_t)k * (ND_ / 4);
            if (k == 0) {
                fused_layer_kernel<0><<<blocks, 256, 0, stream>>>(
                    rowptr, edges, user4, item4, Urows, nullptr,
                    nz, y, out4, N, 1, invL);
            } else {
                fused_layer_kernel<1><<<blocks, 256, 0, stream>>>(
                    rowptr, edges, nullptr, nullptr, 0, (const uint4*)e16[(k - 1) & 1],
                    nz, y, out4, N, 0, invL);
            }
        }
    } else {
        // fallback: round-1 atomic path (fp32 throughout)
        float* egoA = (float*)d_ws;
        float* egoB = egoA + ND_;
        init_zero_kernel<<<(ND + 255) / 256, 256, 0, stream>>>(user, item, egoA, egoB, UD, ND);
        float* cur = egoA;
        float* nxt = egoB;
        for (int k = 0; k < L; ++k) {
            spmm_kernel<<<2048, 256, 0, stream>>>(row, col, val, cur, nxt, nnz);
            perturb_kernel<<<1024, 256, 0, stream>>>(
                nxt, noise + (size_t)k * ND_,
                (k + 1 < L) ? cur : nullptr, out, N, (k == 0) ? 1 : 0, invL);
            float* t = cur; cur = nxt; nxt = t;
        }
    }
}

// Round 6
// 356.553 us; speedup vs baseline: 4.0139x; 1.0543x over previous
//
#include <hip/hip_runtime.h>
#include <hip/hip_fp16.h>

#define DDIM 64
#define EPS 0.1f
#define NORM_EPS 1e-12f

// ---------------- fallback init ----------------
__global__ void init_zero_kernel(const float* __restrict__ user, const float* __restrict__ item,
                                 float* __restrict__ egoA, float* __restrict__ egoB,
                                 int UD, int ND) {
    int i = blockIdx.x * blockDim.x + threadIdx.x;
    if (i < ND) {
        egoA[i] = (i < UD) ? user[i] : item[i - UD];
        egoB[i] = 0.0f;
    }
}

// ---------------- CSR build ----------------
__global__ void zero_int_kernel(int* __restrict__ p, int n) {
    int i = blockIdx.x * blockDim.x + threadIdx.x;
    if (i < n) p[i] = 0;
}

__global__ void hist_kernel(const int* __restrict__ row, int* __restrict__ cnt,
                            int* __restrict__ pos, int nnz) {
    int e = blockIdx.x * blockDim.x + threadIdx.x;
    if (e < nnz) pos[e] = atomicAdd(&cnt[row[e]], 1);
}

__global__ void scan1_kernel(const int* __restrict__ cnt, int* __restrict__ partial,
                             int* __restrict__ bsums, int n) {
    __shared__ int s[1024];
    int i = blockIdx.x * 1024 + threadIdx.x;
    int v = (i < n) ? cnt[i] : 0;
    s[threadIdx.x] = v;
    __syncthreads();
    for (int off = 1; off < 1024; off <<= 1) {
        int t = (threadIdx.x >= off) ? s[threadIdx.x - off] : 0;
        __syncthreads();
        s[threadIdx.x] += t;
        __syncthreads();
    }
    if (i < n) partial[i] = s[threadIdx.x];
    if (threadIdx.x == 1023) bsums[blockIdx.x] = s[1023];
}

__global__ void scan2_kernel(int* __restrict__ bsums, int nb) {
    if (blockIdx.x == 0 && threadIdx.x == 0) {
        int run = 0;
        for (int b = 0; b < nb; ++b) { int t = bsums[b]; bsums[b] = run; run += t; }
    }
}

__global__ void scan3_serialbs_kernel(const int* __restrict__ partial, const int* __restrict__ bsums,
                                      int* __restrict__ rowptr, int n) {
    int i = blockIdx.x * 1024 + threadIdx.x;
    if (i < n) rowptr[i + 1] = partial[i] + bsums[blockIdx.x];
    if (i == 0) rowptr[0] = 0;
}

__global__ void scan3_fused_kernel(const int* __restrict__ partial, const int* __restrict__ bsums,
                                   int* __restrict__ rowptr, int n, int nb) {
    __shared__ int s[1024];
    int t = threadIdx.x;
    s[t] = (t < nb && t < (int)blockIdx.x) ? bsums[t] : 0;
    __syncthreads();
    #pragma unroll
    for (int off = 512; off > 0; off >>= 1) {
        if (t < off) s[t] += s[t + off];
        __syncthreads();
    }
    int base = s[0];
    int i = blockIdx.x * 1024 + t;
    if (i < n) rowptr[i + 1] = partial[i] + base;
    if (i == 0) rowptr[0] = 0;
}

__global__ void scatter_kernel(const int* __restrict__ row, const int* __restrict__ col,
                               const float* __restrict__ val, const int* __restrict__ rowptr,
                               const int* __restrict__ pos, int2* __restrict__ edges, int nnz) {
    int e = blockIdx.x * blockDim.x + threadIdx.x;
    if (e < nnz) {
        int r = row[e];
        edges[rowptr[r] + pos[e]] = make_int2(col[e], __float_as_int(val[e]));
    }
}

// ---------------- fused layer ----------------
// fp32 acc += fp16x2-packed * fp32 scalar, one v_fma_mix_f32 per dim
__device__ __forceinline__ void fma_mix8(float& f0, float& f1, float& f2, float& f3,
                                         float& f4, float& f5, float& f6, float& f7,
                                         uint4 q, float v) {
    asm("v_fma_mix_f32 %0, %8, %12, %0 op_sel:[0,0,0] op_sel_hi:[1,0,0]\n\t"
        "v_fma_mix_f32 %1, %8, %12, %1 op_sel:[1,0,0] op_sel_hi:[1,0,0]\n\t"
        "v_fma_mix_f32 %2, %9, %12, %2 op_sel:[0,0,0] op_sel_hi:[1,0,0]\n\t"
        "v_fma_mix_f32 %3, %9, %12, %3 op_sel:[1,0,0] op_sel_hi:[1,0,0]\n\t"
        "v_fma_mix_f32 %4, %10, %12, %4 op_sel:[0,0,0] op_sel_hi:[1,0,0]\n\t"
        "v_fma_mix_f32 %5, %10, %12, %5 op_sel:[1,0,0] op_sel_hi:[1,0,0]\n\t"
        "v_fma_mix_f32 %6, %11, %12, %6 op_sel:[0,0,0] op_sel_hi:[1,0,0]\n\t"
        "v_fma_mix_f32 %7, %11, %12, %7 op_sel:[1,0,0] op_sel_hi:[1,0,0]"
        : "+v"(f0), "+v"(f1), "+v"(f2), "+v"(f3),
          "+v"(f4), "+v"(f5), "+v"(f6), "+v"(f7)
        : "v"(q.x), "v"(q.y), "v"(q.z), "v"(q.w), "v"(v));
}

// one row per 8-lane group (8 rows/wave); lane sub owns dims [sub*8, sub*8+8).
// Edges serial per group (unroll 2). No cross-group reduce; all lanes active
// in prologue/epilogue. XHALF=0: gather fp32 user/item (layer 0). XHALF=1: fp16 ego.
template <int XHALF>
__global__ void fused_layer_kernel(const int* __restrict__ rowptr, const int2* __restrict__ edges,
                                   const float4* __restrict__ xu4, const float4* __restrict__ xi4,
                                   int splitRow,
                                   const uint4* __restrict__ x16,
                                   const float4* __restrict__ noise4,
                                   uint4* __restrict__ y16, float4* __restrict__ out4,
                                   int N, int first, float invL) {
    int lane = threadIdx.x & 63;
    int wid = (blockIdx.x * blockDim.x + threadIdx.x) >> 6;
    int g   = lane >> 3;   // group = row slot 0..7
    int sub = lane & 7;    // 8-dim chunk within row
    int r = wid * 8 + g;
    bool active = r < N;

    size_t f4idx = (size_t)r * 16 + sub * 2;

    // prologue loads (all lanes active)
    float4 nva = make_float4(0.f,0.f,0.f,0.f), nvb = make_float4(0.f,0.f,0.f,0.f);
    float4 poa = make_float4(0.f,0.f,0.f,0.f), pob = make_float4(0.f,0.f,0.f,0.f);
    int beg = 0, end = 0;
    if (active) {
        beg = rowptr[r];
        end = rowptr[r + 1];
        nva = noise4[f4idx]; nvb = noise4[f4idx + 1];
        if (!first) { poa = out4[f4idx]; pob = out4[f4idx + 1]; }
    }

    float f0=0.f,f1=0.f,f2=0.f,f3=0.f,f4=0.f,f5=0.f,f6=0.f,f7=0.f;

    int e = beg;
    if (XHALF) {
        while (e + 2 <= end) {
            int2 ed0 = edges[e];
            int2 ed1 = edges[e + 1];
            uint4 q0 = x16[(size_t)ed0.x * 8 + sub];
            uint4 q1 = x16[(size_t)ed1.x * 8 + sub];
            fma_mix8(f0,f1,f2,f3,f4,f5,f6,f7, q0, __int_as_float(ed0.y));
            fma_mix8(f0,f1,f2,f3,f4,f5,f6,f7, q1, __int_as_float(ed1.y));
            e += 2;
        }
        if (e < end) {
            int2 ed = edges[e];
            uint4 q = x16[(size_t)ed.x * 8 + sub];
            fma_mix8(f0,f1,f2,f3,f4,f5,f6,f7, q, __int_as_float(ed.y));
        }
    } else {
        while (e < end) {
            int2 ed = edges[e];
            float v = __int_as_float(ed.y);
            const float4* s = (ed.x < splitRow) ? (xu4 + (size_t)ed.x * 16)
                                                : (xi4 + (size_t)(ed.x - splitRow) * 16);
            float4 a = s[sub * 2], b = s[sub * 2 + 1];
            f0 = fmaf(v, a.x, f0); f1 = fmaf(v, a.y, f1);
            f2 = fmaf(v, a.z, f2); f3 = fmaf(v, a.w, f3);
            f4 = fmaf(v, b.x, f4); f5 = fmaf(v, b.y, f5);
            f6 = fmaf(v, b.z, f6); f7 = fmaf(v, b.w, f7);
            ++e;
        }
    }

    // noise L2 norm over the row: local 8 dims + 3-step intra-group reduce
    float sq = nva.x*nva.x + nva.y*nva.y + nva.z*nva.z + nva.w*nva.w
             + nvb.x*nvb.x + nvb.y*nvb.y + nvb.z*nvb.z + nvb.w*nvb.w;
    #pragma unroll
    for (int off = 1; off <= 4; off <<= 1) sq += __shfl_xor(sq, off, 64);
    float scale = EPS / fmaxf(sqrtf(sq), NORM_EPS);

    float acc[8] = {f0,f1,f2,f3,f4,f5,f6,f7};
    float nse[8] = {nva.x,nva.y,nva.z,nva.w,nvb.x,nvb.y,nvb.z,nvb.w};
    float po[8]  = {poa.x,poa.y,poa.z,poa.w,pob.x,pob.y,pob.z,pob.w};
    float ep[8];
    #pragma unroll
    for (int i = 0; i < 8; ++i) {
        float s = (acc[i] > 0.f) ? 1.f : ((acc[i] < 0.f) ? -1.f : 0.f);
        ep[i] = acc[i] + s * nse[i] * scale;
    }

    if (active) {
        if (y16) {
            __half2 h0 = __floats2half2_rn(ep[0], ep[1]);
            __half2 h1 = __floats2half2_rn(ep[2], ep[3]);
            __half2 h2 = __floats2half2_rn(ep[4], ep[5]);
            __half2 h3 = __floats2half2_rn(ep[6], ep[7]);
            uint4 st;
            st.x = *reinterpret_cast<unsigned*>(&h0);
            st.y = *reinterpret_cast<unsigned*>(&h1);
            st.z = *reinterpret_cast<unsigned*>(&h2);
            st.w = *reinterpret_cast<unsigned*>(&h3);
            y16[(size_t)r * 8 + sub] = st;
        }
        float4 oa, ob;
        if (first) {
            oa = make_float4(ep[0]*invL, ep[1]*invL, ep[2]*invL, ep[3]*invL);
            ob = make_float4(ep[4]*invL, ep[5]*invL, ep[6]*invL, ep[7]*invL);
        } else {
            oa = make_float4(fmaf(ep[0],invL,po[0]), fmaf(ep[1],invL,po[1]),
                             fmaf(ep[2],invL,po[2]), fmaf(ep[3],invL,po[3]));
            ob = make_float4(fmaf(ep[4],invL,po[4]), fmaf(ep[5],invL,po[5]),
                             fmaf(ep[6],invL,po[6]), fmaf(ep[7],invL,po[7]));
        }
        out4[f4idx] = oa;
        out4[f4idx + 1] = ob;
    }
}

// ---------------- fallback path (round-1 kernels) ----------------
__global__ void spmm_kernel(const int* __restrict__ row, const int* __restrict__ col,
                            const float* __restrict__ val, const float* __restrict__ x,
                            float* __restrict__ y, int nnz) {
    int gtid = blockIdx.x * blockDim.x + threadIdx.x;
    int wid = gtid >> 6;
    int lane = threadIdx.x & 63;
    int nwaves = (gridDim.x * blockDim.x) >> 6;
    for (int e = wid; e < nnz; e += nwaves) {
        int r = row[e];
        int c = col[e];
        float v = val[e];
        unsafeAtomicAdd(&y[(size_t)r * DDIM + lane], v * x[(size_t)c * DDIM + lane]);
    }
}

__global__ void perturb_kernel(float* __restrict__ ego, const float* __restrict__ noise,
                               float* __restrict__ zero_buf, float* __restrict__ out,
                               int N, int first, float invL) {
    int gtid = blockIdx.x * blockDim.x + threadIdx.x;
    int wid = gtid >> 6;
    int lane = threadIdx.x & 63;
    int nwaves = (gridDim.x * blockDim.x) >> 6;
    for (int n = wid; n < N; n += nwaves) {
        size_t idx = (size_t)n * DDIM + lane;
        float nv = noise[idx];
        float sq = nv * nv;
        #pragma unroll
        for (int off = 32; off > 0; off >>= 1) sq += __shfl_xor(sq, off, 64);
        float rn = nv / fmaxf(sqrtf(sq), NORM_EPS);
        float e = ego[idx];
        float s = (e > 0.0f) ? 1.0f : ((e < 0.0f) ? -1.0f : 0.0f);
        float ep = e + s * rn * EPS;
        ego[idx] = ep;
        if (zero_buf) zero_buf[idx] = 0.0f;
        float o = ep * invL;
        out[idx] = first ? o : (out[idx] + o);
    }
}

extern "C" void kernel_launch(void* const* d_in, const int* in_sizes, int n_in,
                              void* d_out, int out_size, void* d_ws, size_t ws_size,
                              hipStream_t stream) {
    const float* user  = (const float*)d_in[0];
    const float* item  = (const float*)d_in[1];
    const int*   row   = (const int*)d_in[2];
    const int*   col   = (const int*)d_in[3];
    const float* val   = (const float*)d_in[4];
    const float* noise = (const float*)d_in[5];
    float* out = (float*)d_out;

    int UD = in_sizes[0];
    int ID = in_sizes[1];
    int ND = UD + ID;
    int N  = ND / DDIM;
    int nnz = in_sizes[2];
    int L  = in_sizes[5] / ND;
    float invL = 1.0f / (float)L;

    // ws layout (4B units):
    // ego16A(ND/2) | ego16B(ND/2) | rowptr(N+2) | cnt(N) | partial(N) | bsums(1024) | pos(nnz) | edges(2*nnz)
    size_t ND_ = (size_t)ND;
    size_t ofs_rowptr  = ND_;
    size_t ofs_cnt     = ofs_rowptr + (size_t)(N + 2);
    size_t ofs_partial = ofs_cnt + (size_t)N;
    size_t ofs_bsums   = ofs_partial + (size_t)N;
    size_t ofs_pos     = ofs_bsums + 1024;
    size_t ofs_edges   = ofs_pos + (size_t)nnz;
    size_t needed = (ofs_edges + 2ull * (size_t)nnz) * 4ull;

    if (ws_size >= needed && (N % 2) == 0 && (nnz % 2) == 0 && (UD % DDIM) == 0) {
        uint4* ego16A = (uint4*)d_ws;
        uint4* ego16B = (uint4*)((char*)d_ws + 2ull * ND_);   // ND/2 floats = 2*ND bytes
        int* rowptr  = (int*)d_ws + ofs_rowptr;
        int* cnt     = (int*)d_ws + ofs_cnt;
        int* partial = (int*)d_ws + ofs_partial;
        int* bsums   = (int*)d_ws + ofs_bsums;
        int* pos     = (int*)d_ws + ofs_pos;
        int2* edges  = (int2*)((int*)d_ws + ofs_edges);

        int nb = (N + 1023) / 1024;

        zero_int_kernel<<<(N + 255) / 256, 256, 0, stream>>>(cnt, N);
        hist_kernel<<<(nnz + 255) / 256, 256, 0, stream>>>(row, cnt, pos, nnz);
        scan1_kernel<<<nb, 1024, 0, stream>>>(cnt, partial, bsums, N);
        if (nb <= 1024) {
            scan3_fused_kernel<<<nb, 1024, 0, stream>>>(partial, bsums, rowptr, N, nb);
        } else {
            scan2_kernel<<<1, 64, 0, stream>>>(bsums, nb);
            scan3_serialbs_kernel<<<nb, 1024, 0, stream>>>(partial, bsums, rowptr, N);
        }
        scatter_kernel<<<(nnz + 255) / 256, 256, 0, stream>>>(row, col, val, rowptr, pos, edges, nnz);

        const float4* user4 = (const float4*)user;
        const float4* item4 = (const float4*)item;
        const float4* noise4 = (const float4*)noise;
        float4* out4 = (float4*)out;
        int Urows = UD / DDIM;

        int blocks = ((N * 8) + 255) / 256;   // 8 rows per wave
        uint4* e16[2] = { ego16A, ego16B };
        for (int k = 0; k < L; ++k) {
            uint4* y = (k == L - 1) ? nullptr : e16[k & 1];
            const float4* nz = noise4 + (size_t)k * (ND_ / 4);
            if (k == 0) {
                fused_layer_kernel<0><<<blocks, 256, 0, stream>>>(
                    rowptr, edges, user4, item4, Urows, nullptr,
                    nz, y, out4, N, 1, invL);
            } else {
                fused_layer_kernel<1><<<blocks, 256, 0, stream>>>(
                    rowptr, edges, nullptr, nullptr, 0, (const uint4*)e16[(k - 1) & 1],
                    nz, y, out4, N, 0, invL);
            }
        }
    } else {
        // fallback: round-1 atomic path (fp32 throughout)
        float* egoA = (float*)d_ws;
        float* egoB = egoA + ND_;
        init_zero_kernel<<<(ND + 255) / 256, 256, 0, stream>>>(user, item, egoA, egoB, UD, ND);
        float* cur = egoA;
        float* nxt = egoB;
        for (int k = 0; k < L; ++k) {
            spmm_kernel<<<2048, 256, 0, stream>>>(row, col, val, cur, nxt, nnz);
            perturb_kernel<<<1024, 256, 0, stream>>>(
                nxt, noise + (size_t)k * ND_,
                (k + 1 < L) ? cur : nullptr, out, N, (k == 0) ? 1 : 0, invL);
            float* t = cur; cur = nxt; nxt = t;
        }
    }
}